// Round 2
// baseline (5524.668 us; speedup 1.0000x reference)
//
#include <hip/hip_runtime.h>

#define D 128
#define TILE_ROWS 64
#define MLP_THREADS 512

// ---------------------------------------------------------------------------
// K1: out = x  (agg initialized to x, since h = (1+eps)*x + agg with eps=0)
// ---------------------------------------------------------------------------
__global__ void init_kernel(const float* __restrict__ x, float* __restrict__ out, int n4) {
    int i = blockIdx.x * blockDim.x + threadIdx.x;
    if (i < n4) {
        reinterpret_cast<float4*>(out)[i] = reinterpret_cast<const float4*>(x)[i];
    }
}

// ---------------------------------------------------------------------------
// K2: scatter-add  out[dst] += x[src]  (32 lanes per edge, float4 per lane)
// edge_index arrives as int32 (harness converts integer inputs to int32).
// ---------------------------------------------------------------------------
__global__ void scatter_kernel(const float* __restrict__ x,
                               const int* __restrict__ ei,
                               float* __restrict__ out, int ne) {
    long long gid = (long long)blockIdx.x * blockDim.x + threadIdx.x;
    int e = (int)(gid >> 5);
    if (e >= ne) return;
    int d0 = ((int)gid & 31) * 4;
    int src = ei[e];
    int dst = ei[ne + e];
    float4 v = *reinterpret_cast<const float4*>(x + (long long)src * D + d0);
    float* o = out + (long long)dst * D + d0;
    atomicAdd(o + 0, v.x);
    atomicAdd(o + 1, v.y);
    atomicAdd(o + 2, v.z);
    atomicAdd(o + 3, v.w);
}

// ---------------------------------------------------------------------------
// K3/K4: in-place row-tile GEMM  out[r] = act(in[r] @ W + b)
// 64-row tile per block, 512 threads, each thread computes 4 rows x 4 cols.
// W (64KB) + input tile (33KB) staged in LDS (97KB static, gfx950 has 160KB).
// In-place safe: all global reads of the tile happen before __syncthreads,
// writes after; rows are block-local.
// ---------------------------------------------------------------------------
template <bool RELU>
__global__ __launch_bounds__(MLP_THREADS, 1) void mlp_kernel(
    const float* __restrict__ in, const float* __restrict__ W,
    const float* __restrict__ b, float* __restrict__ outp, int nrows) {
    __shared__ float Wl[D][D];                 // 64 KB, same layout as global W[k][c]
    __shared__ float inl[TILE_ROWS][D + 4];    // +4 pad: bank-spread, keeps 16B align

    const int tid = threadIdx.x;
    const int row0 = blockIdx.x * TILE_ROWS;

    // stage W (4096 float4, coalesced, contiguous LDS writes)
    for (int i = tid; i < D * D / 4; i += MLP_THREADS) {
        reinterpret_cast<float4*>(&Wl[0][0])[i] =
            reinterpret_cast<const float4*>(W)[i];
    }
    // stage input tile (2048 float4)
    for (int i = tid; i < TILE_ROWS * (D / 4); i += MLP_THREADS) {
        int r = i >> 5;       // 32 float4 per row
        int k4 = i & 31;
        float4 v = make_float4(0.f, 0.f, 0.f, 0.f);
        if (row0 + r < nrows)
            v = *reinterpret_cast<const float4*>(in + (size_t)(row0 + r) * D + 4 * k4);
        *reinterpret_cast<float4*>(&inl[r][4 * k4]) = v;
    }
    __syncthreads();

    const int cg = tid & 31;   // col group: cols 4*cg .. 4*cg+3
    const int rg = tid >> 5;   // row group: rows 4*rg .. 4*rg+3
    const int c0 = cg * 4;
    const int r0 = rg * 4;

    float4 bv = *reinterpret_cast<const float4*>(b + c0);
    float acc[4][4];
#pragma unroll
    for (int i = 0; i < 4; ++i) {
        acc[i][0] = bv.x; acc[i][1] = bv.y; acc[i][2] = bv.z; acc[i][3] = bv.w;
    }

#pragma unroll 4
    for (int k4 = 0; k4 < 32; ++k4) {
        float4 w0 = *reinterpret_cast<const float4*>(&Wl[4 * k4 + 0][c0]);
        float4 w1 = *reinterpret_cast<const float4*>(&Wl[4 * k4 + 1][c0]);
        float4 w2 = *reinterpret_cast<const float4*>(&Wl[4 * k4 + 2][c0]);
        float4 w3 = *reinterpret_cast<const float4*>(&Wl[4 * k4 + 3][c0]);
#pragma unroll
        for (int i = 0; i < 4; ++i) {
            float4 a = *reinterpret_cast<const float4*>(&inl[r0 + i][4 * k4]);
            acc[i][0] += a.x * w0.x + a.y * w1.x + a.z * w2.x + a.w * w3.x;
            acc[i][1] += a.x * w0.y + a.y * w1.y + a.z * w2.y + a.w * w3.y;
            acc[i][2] += a.x * w0.z + a.y * w1.z + a.z * w2.z + a.w * w3.z;
            acc[i][3] += a.x * w0.w + a.y * w1.w + a.z * w2.w + a.w * w3.w;
        }
    }

#pragma unroll
    for (int i = 0; i < 4; ++i) {
        int r = row0 + r0 + i;
        if (r < nrows) {
            float4 o;
            if (RELU) {
                o.x = fmaxf(acc[i][0], 0.f); o.y = fmaxf(acc[i][1], 0.f);
                o.z = fmaxf(acc[i][2], 0.f); o.w = fmaxf(acc[i][3], 0.f);
            } else {
                o.x = acc[i][0]; o.y = acc[i][1]; o.z = acc[i][2]; o.w = acc[i][3];
            }
            *reinterpret_cast<float4*>(outp + (size_t)r * D + c0) = o;
        }
    }
}

extern "C" void kernel_launch(void* const* d_in, const int* in_sizes, int n_in,
                              void* d_out, int out_size, void* d_ws, size_t ws_size,
                              hipStream_t stream) {
    const float* x = (const float*)d_in[0];
    const int* ei = (const int*)d_in[1];
    const float* W1 = (const float*)d_in[2];
    const float* b1 = (const float*)d_in[3];
    const float* W2 = (const float*)d_in[4];
    const float* b2 = (const float*)d_in[5];
    float* out = (float*)d_out;

    const int nrows = in_sizes[0] / D;
    const int ne = in_sizes[1] / 2;

    // K1: out = x
    int n4 = nrows * (D / 4);
    init_kernel<<<(n4 + 255) / 256, 256, 0, stream>>>(x, out, n4);

    // K2: out[dst] += x[src]
    long long sthreads = (long long)ne * 32;
    int sblocks = (int)((sthreads + 255) / 256);
    scatter_kernel<<<sblocks, 256, 0, stream>>>(x, ei, out, ne);

    // K3: out = relu(out @ W1 + b1)   (in-place, row-local)
    int mblocks = (nrows + TILE_ROWS - 1) / TILE_ROWS;
    mlp_kernel<true><<<mblocks, MLP_THREADS, 0, stream>>>(out, W1, b1, out, nrows);

    // K4: out = out @ W2 + b2         (in-place, row-local)
    mlp_kernel<false><<<mblocks, MLP_THREADS, 0, stream>>>(out, W2, b2, out, nrows);
}

// Round 3
// 1121.466 us; speedup vs baseline: 4.9263x; 4.9263x over previous
//
#include <hip/hip_runtime.h>

#define D 128
#define TILE_ROWS 64
#define MLP_THREADS 512
#define SCAN_THREADS 1024

// ---------------------------------------------------------------------------
// CSR build: zero -> hist -> scan -> fill, then gather-based aggregation.
// ---------------------------------------------------------------------------
__global__ void zero_kernel(int* __restrict__ p, int n) {
    int i = blockIdx.x * blockDim.x + threadIdx.x;
    if (i < n) p[i] = 0;
}

__global__ void hist_kernel(const int* __restrict__ dsts, int* __restrict__ counts, int ne) {
    int e = blockIdx.x * blockDim.x + threadIdx.x;
    if (e < ne) atomicAdd(&counts[dsts[e]], 1);
}

// Single-block exclusive scan over n counts. counts==cursor buffer on entry;
// writes offsets[0..n] (offsets[n]=total) and resets cursor to bucket starts.
__global__ __launch_bounds__(SCAN_THREADS) void scan_kernel(
    const int* __restrict__ counts, int* __restrict__ offsets,
    int* __restrict__ cursor, int n) {
    __shared__ int stot[SCAN_THREADS];
    const int t = threadIdx.x;
    const int chunk = (n + SCAN_THREADS - 1) / SCAN_THREADS;
    const int beg = t * chunk;
    const int end = min(beg + chunk, n);

    int total = 0;
    for (int i = beg; i < end; ++i) total += counts[i];
    stot[t] = total;
    __syncthreads();
    // Hillis-Steele inclusive scan of per-thread totals
    for (int off = 1; off < SCAN_THREADS; off <<= 1) {
        int v = (t >= off) ? stot[t - off] : 0;
        __syncthreads();
        stot[t] += v;
        __syncthreads();
    }
    int base = stot[t] - total;  // exclusive base for this thread's chunk
    for (int i = beg; i < end; ++i) {
        int c = counts[i];
        offsets[i] = base;
        cursor[i] = base;
        base += c;
    }
    if (t == SCAN_THREADS - 1) offsets[n] = base;
}

__global__ void fill_kernel(const int* __restrict__ ei, int* __restrict__ cursor,
                            int* __restrict__ sorted_src, int ne) {
    int e = blockIdx.x * blockDim.x + threadIdx.x;
    if (e >= ne) return;
    int dst = ei[ne + e];
    int pos = atomicAdd(&cursor[dst], 1);
    sorted_src[pos] = ei[e];
}

// One 64-lane wave per node; lane holds float2 (128 dims / 64 lanes).
// acc starts at x[node] (eps=0), adds each in-neighbor row, writes out once.
__global__ void agg_kernel(const float* __restrict__ x,
                           const int* __restrict__ sorted_src,
                           const int* __restrict__ offsets,
                           float* __restrict__ out, int nnodes) {
    int gid = blockIdx.x * blockDim.x + threadIdx.x;
    int node = gid >> 6;
    if (node >= nnodes) return;
    int lane = threadIdx.x & 63;
    const float2* xp = reinterpret_cast<const float2*>(x);
    int beg = offsets[node];
    int end = offsets[node + 1];
    float2 acc = xp[(size_t)node * 64 + lane];
    for (int i = beg; i < end; ++i) {
        int s = sorted_src[i];
        float2 v = xp[(size_t)s * 64 + lane];
        acc.x += v.x;
        acc.y += v.y;
    }
    reinterpret_cast<float2*>(out)[(size_t)node * 64 + lane] = acc;
}

// ---------------------------------------------------------------------------
// Fallback (ws too small): init + fp32 atomic scatter (round-2 path)
// ---------------------------------------------------------------------------
__global__ void init_kernel(const float* __restrict__ x, float* __restrict__ out, int n4) {
    int i = blockIdx.x * blockDim.x + threadIdx.x;
    if (i < n4) {
        reinterpret_cast<float4*>(out)[i] = reinterpret_cast<const float4*>(x)[i];
    }
}

__global__ void scatter_kernel(const float* __restrict__ x,
                               const int* __restrict__ ei,
                               float* __restrict__ out, int ne) {
    long long gid = (long long)blockIdx.x * blockDim.x + threadIdx.x;
    int e = (int)(gid >> 5);
    if (e >= ne) return;
    int d0 = ((int)gid & 31) * 4;
    int src = ei[e];
    int dst = ei[ne + e];
    float4 v = *reinterpret_cast<const float4*>(x + (long long)src * D + d0);
    float* o = out + (long long)dst * D + d0;
    atomicAdd(o + 0, v.x);
    atomicAdd(o + 1, v.y);
    atomicAdd(o + 2, v.z);
    atomicAdd(o + 3, v.w);
}

// ---------------------------------------------------------------------------
// K3/K4: in-place row-tile GEMM  out[r] = act(in[r] @ W + b)
// ---------------------------------------------------------------------------
template <bool RELU>
__global__ __launch_bounds__(MLP_THREADS, 1) void mlp_kernel(
    const float* __restrict__ in, const float* __restrict__ W,
    const float* __restrict__ b, float* __restrict__ outp, int nrows) {
    __shared__ float Wl[D][D];
    __shared__ float inl[TILE_ROWS][D + 4];

    const int tid = threadIdx.x;
    const int row0 = blockIdx.x * TILE_ROWS;

    for (int i = tid; i < D * D / 4; i += MLP_THREADS) {
        reinterpret_cast<float4*>(&Wl[0][0])[i] =
            reinterpret_cast<const float4*>(W)[i];
    }
    for (int i = tid; i < TILE_ROWS * (D / 4); i += MLP_THREADS) {
        int r = i >> 5;
        int k4 = i & 31;
        float4 v = make_float4(0.f, 0.f, 0.f, 0.f);
        if (row0 + r < nrows)
            v = *reinterpret_cast<const float4*>(in + (size_t)(row0 + r) * D + 4 * k4);
        *reinterpret_cast<float4*>(&inl[r][4 * k4]) = v;
    }
    __syncthreads();

    const int cg = tid & 31;
    const int rg = tid >> 5;
    const int c0 = cg * 4;
    const int r0 = rg * 4;

    float4 bv = *reinterpret_cast<const float4*>(b + c0);
    float acc[4][4];
#pragma unroll
    for (int i = 0; i < 4; ++i) {
        acc[i][0] = bv.x; acc[i][1] = bv.y; acc[i][2] = bv.z; acc[i][3] = bv.w;
    }

#pragma unroll 4
    for (int k4 = 0; k4 < 32; ++k4) {
        float4 w0 = *reinterpret_cast<const float4*>(&Wl[4 * k4 + 0][c0]);
        float4 w1 = *reinterpret_cast<const float4*>(&Wl[4 * k4 + 1][c0]);
        float4 w2 = *reinterpret_cast<const float4*>(&Wl[4 * k4 + 2][c0]);
        float4 w3 = *reinterpret_cast<const float4*>(&Wl[4 * k4 + 3][c0]);
#pragma unroll
        for (int i = 0; i < 4; ++i) {
            float4 a = *reinterpret_cast<const float4*>(&inl[r0 + i][4 * k4]);
            acc[i][0] += a.x * w0.x + a.y * w1.x + a.z * w2.x + a.w * w3.x;
            acc[i][1] += a.x * w0.y + a.y * w1.y + a.z * w2.y + a.w * w3.y;
            acc[i][2] += a.x * w0.z + a.y * w1.z + a.z * w2.z + a.w * w3.z;
            acc[i][3] += a.x * w0.w + a.y * w1.w + a.z * w2.w + a.w * w3.w;
        }
    }

#pragma unroll
    for (int i = 0; i < 4; ++i) {
        int r = row0 + r0 + i;
        if (r < nrows) {
            float4 o;
            if (RELU) {
                o.x = fmaxf(acc[i][0], 0.f); o.y = fmaxf(acc[i][1], 0.f);
                o.z = fmaxf(acc[i][2], 0.f); o.w = fmaxf(acc[i][3], 0.f);
            } else {
                o.x = acc[i][0]; o.y = acc[i][1]; o.z = acc[i][2]; o.w = acc[i][3];
            }
            *reinterpret_cast<float4*>(outp + (size_t)r * D + c0) = o;
        }
    }
}

extern "C" void kernel_launch(void* const* d_in, const int* in_sizes, int n_in,
                              void* d_out, int out_size, void* d_ws, size_t ws_size,
                              hipStream_t stream) {
    const float* x = (const float*)d_in[0];
    const int* ei = (const int*)d_in[1];
    const float* W1 = (const float*)d_in[2];
    const float* b1 = (const float*)d_in[3];
    const float* W2 = (const float*)d_in[4];
    const float* b2 = (const float*)d_in[5];
    float* out = (float*)d_out;

    const int nrows = in_sizes[0] / D;     // 100000 nodes
    const int ne = in_sizes[1] / 2;        // 3200000 edges

    // ws layout: offsets[nrows+1] | cursor[nrows] | sorted_src[ne]   (ints)
    size_t need = ((size_t)(nrows + 1) + nrows + ne) * sizeof(int);

    if (ws_size >= need) {
        int* offsets = (int*)d_ws;
        int* cursor = offsets + (nrows + 1);
        int* sorted_src = cursor + nrows;

        zero_kernel<<<(nrows + 255) / 256, 256, 0, stream>>>(cursor, nrows);
        hist_kernel<<<(ne + 255) / 256, 256, 0, stream>>>(ei + ne, cursor, ne);
        scan_kernel<<<1, SCAN_THREADS, 0, stream>>>(cursor, offsets, cursor, nrows);
        fill_kernel<<<(ne + 255) / 256, 256, 0, stream>>>(ei, cursor, sorted_src, ne);

        long long athreads = (long long)nrows * 64;
        agg_kernel<<<(int)((athreads + 255) / 256), 256, 0, stream>>>(
            x, sorted_src, offsets, out, nrows);
    } else {
        // fallback: atomic scatter
        int n4 = nrows * (D / 4);
        init_kernel<<<(n4 + 255) / 256, 256, 0, stream>>>(x, out, n4);
        long long sthreads = (long long)ne * 32;
        scatter_kernel<<<(int)((sthreads + 255) / 256), 256, 0, stream>>>(x, ei, out, ne);
    }

    int mblocks = (nrows + TILE_ROWS - 1) / TILE_ROWS;
    mlp_kernel<true><<<mblocks, MLP_THREADS, 0, stream>>>(out, W1, b1, out, nrows);
    mlp_kernel<false><<<mblocks, MLP_THREADS, 0, stream>>>(out, W2, b2, out, nrows);
}

// Round 4
// 499.740 us; speedup vs baseline: 11.0551x; 2.2441x over previous
//
#include <hip/hip_runtime.h>

#define D 128
#define TILE_ROWS 64
#define MLP_THREADS 512
#define SCAN_THREADS 1024
#define BK_NODES 128     // dst-nodes per coarse bucket
#define MAX_BKT 1024
#define EPB 16           // edges per thread in coarse passes

// ===========================================================================
// New CSR build: coarse bucketing with LDS-privatized histograms.
// pairs[] holds (src<<7)|(dst&127) packed ints, grouped by coarse bucket.
// ===========================================================================
__global__ void zero_kernel(int* __restrict__ p, int n) {
    int i = blockIdx.x * blockDim.x + threadIdx.x;
    if (i < n) p[i] = 0;
}

// A1: per-block LDS hist over coarse buckets, then one global add per bin.
__global__ void coarse_hist_kernel(const int* __restrict__ dsts,
                                   int* __restrict__ ghist, int ne, int nbkt) {
    __shared__ int h[MAX_BKT];
    for (int k = threadIdx.x; k < nbkt; k += blockDim.x) h[k] = 0;
    __syncthreads();
    int base = blockIdx.x * blockDim.x * EPB;
    for (int j = 0; j < EPB; ++j) {
        int e = base + j * blockDim.x + threadIdx.x;
        if (e < ne) atomicAdd(&h[dsts[e] >> 7], 1);
    }
    __syncthreads();
    for (int k = threadIdx.x; k < nbkt; k += blockDim.x)
        if (h[k]) atomicAdd(&ghist[k], h[k]);
}

// A2: single-block scan over nbkt (<=1024) coarse counts.
__global__ __launch_bounds__(SCAN_THREADS) void coarse_scan_kernel(
    const int* __restrict__ ghist, int* __restrict__ cbase,
    int* __restrict__ ccursor, int* __restrict__ offsets,
    int nbkt, int nnodes, int ne) {
    __shared__ int sc[SCAN_THREADS];
    int t = threadIdx.x;
    int v = (t < nbkt) ? ghist[t] : 0;
    sc[t] = v;
    __syncthreads();
    for (int off = 1; off < SCAN_THREADS; off <<= 1) {
        int u = (t >= off) ? sc[t - off] : 0;
        __syncthreads();
        sc[t] += u;
        __syncthreads();
    }
    if (t < nbkt) { cbase[t] = sc[t] - v; ccursor[t] = sc[t] - v; }
    if (t == 0) { cbase[nbkt] = sc[SCAN_THREADS - 1]; offsets[nnodes] = ne; }
}

// A3: scatter packed edges into coarse buckets. LDS hist -> one reservation
// per (block,bucket) -> LDS cursors give in-block positions.
__global__ void coarse_scatter_kernel(const int* __restrict__ ei,
                                      int* __restrict__ ccursor,
                                      int* __restrict__ pairs, int ne, int nbkt) {
    __shared__ int h[MAX_BKT];
    __shared__ int cur[MAX_BKT];
    for (int k = threadIdx.x; k < nbkt; k += blockDim.x) h[k] = 0;
    __syncthreads();
    int base = blockIdx.x * blockDim.x * EPB;
    for (int j = 0; j < EPB; ++j) {
        int e = base + j * blockDim.x + threadIdx.x;
        if (e < ne) atomicAdd(&h[ei[ne + e] >> 7], 1);
    }
    __syncthreads();
    for (int k = threadIdx.x; k < nbkt; k += blockDim.x)
        cur[k] = h[k] ? atomicAdd(&ccursor[k], h[k]) : 0;
    __syncthreads();
    for (int j = 0; j < EPB; ++j) {
        int e = base + j * blockDim.x + threadIdx.x;
        if (e < ne) {
            int dst = ei[ne + e];
            int src = ei[e];
            int k = dst >> 7;
            int pos = atomicAdd(&cur[k], 1);
            pairs[pos] = (src << 7) | (dst & (BK_NODES - 1));
        }
    }
}

// B: one block per coarse bucket; per-node CSR within the bucket via LDS.
__global__ void bucket_csr_kernel(const int* __restrict__ pairs,
                                  const int* __restrict__ cbase,
                                  int* __restrict__ offsets,
                                  int* __restrict__ sorted_src,
                                  int nnodes) {
    __shared__ int h[BK_NODES];
    __shared__ int ex[BK_NODES];
    __shared__ int cur[BK_NODES];
    int b = blockIdx.x;
    int t = threadIdx.x;
    int rbeg = cbase[b], rend = cbase[b + 1];
    if (t < BK_NODES) h[t] = 0;
    __syncthreads();
    for (int i = rbeg + t; i < rend; i += blockDim.x)
        atomicAdd(&h[pairs[i] & (BK_NODES - 1)], 1);
    __syncthreads();
    if (t < BK_NODES) ex[t] = h[t];
    __syncthreads();
    for (int off = 1; off < BK_NODES; off <<= 1) {
        int u = (t >= off && t < BK_NODES) ? ex[t - off] : 0;
        __syncthreads();
        if (t < BK_NODES) ex[t] += u;
        __syncthreads();
    }
    if (t < BK_NODES) {
        int e = ex[t] - h[t];          // exclusive within bucket
        cur[t] = rbeg + e;
        int node = b * BK_NODES + t;
        if (node < nnodes) offsets[node] = rbeg + e;
    }
    __syncthreads();
    for (int i = rbeg + t; i < rend; i += blockDim.x) {
        int p = pairs[i];
        int pos = atomicAdd(&cur[p & (BK_NODES - 1)], 1);
        sorted_src[pos] = p >> 7;
    }
}

// ===========================================================================
// agg: one wave per node, float2 per lane, neighbor loop unrolled x8
// (8 independent 512B row-gathers in flight per wave).
// ===========================================================================
__global__ void agg_kernel(const float* __restrict__ x,
                           const int* __restrict__ sorted_src,
                           const int* __restrict__ offsets,
                           float* __restrict__ out, int nnodes) {
    int gid = blockIdx.x * blockDim.x + threadIdx.x;
    int node = gid >> 6;
    if (node >= nnodes) return;
    int lane = threadIdx.x & 63;
    const float2* xp = reinterpret_cast<const float2*>(x);
    int beg = offsets[node];
    int end = offsets[node + 1];
    float2 a = xp[(size_t)node * 64 + lane];
    float sx = a.x, sy = a.y;
    int i = beg;
    for (; i + 8 <= end; i += 8) {
        int s0 = sorted_src[i + 0], s1 = sorted_src[i + 1];
        int s2 = sorted_src[i + 2], s3 = sorted_src[i + 3];
        int s4 = sorted_src[i + 4], s5 = sorted_src[i + 5];
        int s6 = sorted_src[i + 6], s7 = sorted_src[i + 7];
        float2 v0 = xp[(size_t)s0 * 64 + lane];
        float2 v1 = xp[(size_t)s1 * 64 + lane];
        float2 v2 = xp[(size_t)s2 * 64 + lane];
        float2 v3 = xp[(size_t)s3 * 64 + lane];
        float2 v4 = xp[(size_t)s4 * 64 + lane];
        float2 v5 = xp[(size_t)s5 * 64 + lane];
        float2 v6 = xp[(size_t)s6 * 64 + lane];
        float2 v7 = xp[(size_t)s7 * 64 + lane];
        sx += ((v0.x + v1.x) + (v2.x + v3.x)) + ((v4.x + v5.x) + (v6.x + v7.x));
        sy += ((v0.y + v1.y) + (v2.y + v3.y)) + ((v4.y + v5.y) + (v6.y + v7.y));
    }
    for (; i < end; ++i) {
        int s = sorted_src[i];
        float2 v = xp[(size_t)s * 64 + lane];
        sx += v.x;
        sy += v.y;
    }
    float2 o;
    o.x = sx;
    o.y = sy;
    reinterpret_cast<float2*>(out)[(size_t)node * 64 + lane] = o;
}

// ===========================================================================
// Fallback kernels (old paths, used only if ws is too small)
// ===========================================================================
__global__ void hist_kernel(const int* __restrict__ dsts, int* __restrict__ counts, int ne) {
    int e = blockIdx.x * blockDim.x + threadIdx.x;
    if (e < ne) atomicAdd(&counts[dsts[e]], 1);
}

__global__ __launch_bounds__(SCAN_THREADS) void scan_kernel(
    const int* __restrict__ counts, int* __restrict__ offsets,
    int* __restrict__ cursor, int n) {
    __shared__ int stot[SCAN_THREADS];
    const int t = threadIdx.x;
    const int chunk = (n + SCAN_THREADS - 1) / SCAN_THREADS;
    const int beg = t * chunk;
    const int end = min(beg + chunk, n);
    int total = 0;
    for (int i = beg; i < end; ++i) total += counts[i];
    stot[t] = total;
    __syncthreads();
    for (int off = 1; off < SCAN_THREADS; off <<= 1) {
        int v = (t >= off) ? stot[t - off] : 0;
        __syncthreads();
        stot[t] += v;
        __syncthreads();
    }
    int base = stot[t] - total;
    for (int i = beg; i < end; ++i) {
        int c = counts[i];
        offsets[i] = base;
        cursor[i] = base;
        base += c;
    }
    if (t == SCAN_THREADS - 1) offsets[n] = base;
}

__global__ void fill_kernel(const int* __restrict__ ei, int* __restrict__ cursor,
                            int* __restrict__ sorted_src, int ne) {
    int e = blockIdx.x * blockDim.x + threadIdx.x;
    if (e >= ne) return;
    int dst = ei[ne + e];
    int pos = atomicAdd(&cursor[dst], 1);
    sorted_src[pos] = ei[e];
}

__global__ void init_kernel(const float* __restrict__ x, float* __restrict__ out, int n4) {
    int i = blockIdx.x * blockDim.x + threadIdx.x;
    if (i < n4) {
        reinterpret_cast<float4*>(out)[i] = reinterpret_cast<const float4*>(x)[i];
    }
}

__global__ void scatter_kernel(const float* __restrict__ x,
                               const int* __restrict__ ei,
                               float* __restrict__ out, int ne) {
    long long gid = (long long)blockIdx.x * blockDim.x + threadIdx.x;
    int e = (int)(gid >> 5);
    if (e >= ne) return;
    int d0 = ((int)gid & 31) * 4;
    int src = ei[e];
    int dst = ei[ne + e];
    float4 v = *reinterpret_cast<const float4*>(x + (long long)src * D + d0);
    float* o = out + (long long)dst * D + d0;
    atomicAdd(o + 0, v.x);
    atomicAdd(o + 1, v.y);
    atomicAdd(o + 2, v.z);
    atomicAdd(o + 3, v.w);
}

// ===========================================================================
// MLP: in-place row-tile GEMM  out[r] = act(in[r] @ W + b)
// ===========================================================================
template <bool RELU>
__global__ __launch_bounds__(MLP_THREADS, 1) void mlp_kernel(
    const float* __restrict__ in, const float* __restrict__ W,
    const float* __restrict__ b, float* __restrict__ outp, int nrows) {
    __shared__ float Wl[D][D];
    __shared__ float inl[TILE_ROWS][D + 4];

    const int tid = threadIdx.x;
    const int row0 = blockIdx.x * TILE_ROWS;

    for (int i = tid; i < D * D / 4; i += MLP_THREADS) {
        reinterpret_cast<float4*>(&Wl[0][0])[i] =
            reinterpret_cast<const float4*>(W)[i];
    }
    for (int i = tid; i < TILE_ROWS * (D / 4); i += MLP_THREADS) {
        int r = i >> 5;
        int k4 = i & 31;
        float4 v = make_float4(0.f, 0.f, 0.f, 0.f);
        if (row0 + r < nrows)
            v = *reinterpret_cast<const float4*>(in + (size_t)(row0 + r) * D + 4 * k4);
        *reinterpret_cast<float4*>(&inl[r][4 * k4]) = v;
    }
    __syncthreads();

    const int cg = tid & 31;
    const int rg = tid >> 5;
    const int c0 = cg * 4;
    const int r0 = rg * 4;

    float4 bv = *reinterpret_cast<const float4*>(b + c0);
    float acc[4][4];
#pragma unroll
    for (int i = 0; i < 4; ++i) {
        acc[i][0] = bv.x; acc[i][1] = bv.y; acc[i][2] = bv.z; acc[i][3] = bv.w;
    }

#pragma unroll 4
    for (int k4 = 0; k4 < 32; ++k4) {
        float4 w0 = *reinterpret_cast<const float4*>(&Wl[4 * k4 + 0][c0]);
        float4 w1 = *reinterpret_cast<const float4*>(&Wl[4 * k4 + 1][c0]);
        float4 w2 = *reinterpret_cast<const float4*>(&Wl[4 * k4 + 2][c0]);
        float4 w3 = *reinterpret_cast<const float4*>(&Wl[4 * k4 + 3][c0]);
#pragma unroll
        for (int i = 0; i < 4; ++i) {
            float4 a = *reinterpret_cast<const float4*>(&inl[r0 + i][4 * k4]);
            acc[i][0] += a.x * w0.x + a.y * w1.x + a.z * w2.x + a.w * w3.x;
            acc[i][1] += a.x * w0.y + a.y * w1.y + a.z * w2.y + a.w * w3.y;
            acc[i][2] += a.x * w0.z + a.y * w1.z + a.z * w2.z + a.w * w3.z;
            acc[i][3] += a.x * w0.w + a.y * w1.w + a.z * w2.w + a.w * w3.w;
        }
    }

#pragma unroll
    for (int i = 0; i < 4; ++i) {
        int r = row0 + r0 + i;
        if (r < nrows) {
            float4 o;
            if (RELU) {
                o.x = fmaxf(acc[i][0], 0.f); o.y = fmaxf(acc[i][1], 0.f);
                o.z = fmaxf(acc[i][2], 0.f); o.w = fmaxf(acc[i][3], 0.f);
            } else {
                o.x = acc[i][0]; o.y = acc[i][1]; o.z = acc[i][2]; o.w = acc[i][3];
            }
            *reinterpret_cast<float4*>(outp + (size_t)r * D + c0) = o;
        }
    }
}

extern "C" void kernel_launch(void* const* d_in, const int* in_sizes, int n_in,
                              void* d_out, int out_size, void* d_ws, size_t ws_size,
                              hipStream_t stream) {
    const float* x = (const float*)d_in[0];
    const int* ei = (const int*)d_in[1];
    const float* W1 = (const float*)d_in[2];
    const float* b1 = (const float*)d_in[3];
    const float* W2 = (const float*)d_in[4];
    const float* b2 = (const float*)d_in[5];
    float* out = (float*)d_out;

    const int nrows = in_sizes[0] / D;     // 100000 nodes
    const int ne = in_sizes[1] / 2;        // 3200000 edges
    const int nbkt = (nrows + BK_NODES - 1) / BK_NODES;

    // new-path ws: offsets[nrows+1] | sorted_src[ne] | pairs[ne]
    //            | ghist[nbkt] | cbase[nbkt+1] | ccursor[nbkt]
    size_t need_new = ((size_t)(nrows + 1) + 2 * (size_t)ne + 3 * (size_t)nbkt + 1) * sizeof(int);
    size_t need_old = ((size_t)(nrows + 1) + nrows + ne) * sizeof(int);

    const int eblocks = (ne + 256 * EPB - 1) / (256 * EPB);

    if (ws_size >= need_new && nbkt <= MAX_BKT) {
        int* offsets = (int*)d_ws;
        int* sorted_src = offsets + (nrows + 1);
        int* pairs = sorted_src + ne;
        int* ghist = pairs + ne;
        int* cbase = ghist + nbkt;
        int* ccursor = cbase + (nbkt + 1);

        zero_kernel<<<(nbkt + 255) / 256, 256, 0, stream>>>(ghist, nbkt);
        coarse_hist_kernel<<<eblocks, 256, 0, stream>>>(ei + ne, ghist, ne, nbkt);
        coarse_scan_kernel<<<1, SCAN_THREADS, 0, stream>>>(ghist, cbase, ccursor,
                                                           offsets, nbkt, nrows, ne);
        coarse_scatter_kernel<<<eblocks, 256, 0, stream>>>(ei, ccursor, pairs, ne, nbkt);
        bucket_csr_kernel<<<nbkt, 256, 0, stream>>>(pairs, cbase, offsets, sorted_src, nrows);

        long long athreads = (long long)nrows * 64;
        agg_kernel<<<(int)((athreads + 255) / 256), 256, 0, stream>>>(
            x, sorted_src, offsets, out, nrows);
    } else if (ws_size >= need_old) {
        int* offsets = (int*)d_ws;
        int* cursor = offsets + (nrows + 1);
        int* sorted_src = cursor + nrows;

        zero_kernel<<<(nrows + 255) / 256, 256, 0, stream>>>(cursor, nrows);
        hist_kernel<<<(ne + 255) / 256, 256, 0, stream>>>(ei + ne, cursor, ne);
        scan_kernel<<<1, SCAN_THREADS, 0, stream>>>(cursor, offsets, cursor, nrows);
        fill_kernel<<<(ne + 255) / 256, 256, 0, stream>>>(ei, cursor, sorted_src, ne);

        long long athreads = (long long)nrows * 64;
        agg_kernel<<<(int)((athreads + 255) / 256), 256, 0, stream>>>(
            x, sorted_src, offsets, out, nrows);
    } else {
        int n4 = nrows * (D / 4);
        init_kernel<<<(n4 + 255) / 256, 256, 0, stream>>>(x, out, n4);
        long long sthreads = (long long)ne * 32;
        scatter_kernel<<<(int)((sthreads + 255) / 256), 256, 0, stream>>>(x, ei, out, ne);
    }

    int mblocks = (nrows + TILE_ROWS - 1) / TILE_ROWS;
    mlp_kernel<true><<<mblocks, MLP_THREADS, 0, stream>>>(out, W1, b1, out, nrows);
    mlp_kernel<false><<<mblocks, MLP_THREADS, 0, stream>>>(out, W2, b2, out, nrows);
}